// Round 2
// baseline (2794.347 us; speedup 1.0000x reference)
//
#include <hip/hip_runtime.h>
#include <hip/hip_bf16.h>

#define N_NODES  100000
#define N_EDGES  1600000
#define N_GRAPHS 2000
#define F_IN     32
#define H        64
#define N_LAYERS 5
#define LN_EPS   1e-5f

// ---------------- input projection: h = relu(x @ W_in + b_in) ----------------
__global__ __launch_bounds__(256) void k_input_proj(
        const float* __restrict__ x, const float* __restrict__ Win,
        const float* __restrict__ bin, float* __restrict__ h)
{
    __shared__ float Ws[F_IN * H];
    __shared__ float bs[H];
    int tid = threadIdx.x;
    for (int i = tid; i < F_IN * H; i += 256) Ws[i] = Win[i];
    if (tid < H) bs[tid] = bin[tid];
    __syncthreads();
    int lane = tid & 63;
    int wid  = tid >> 6;
    for (int n = blockIdx.x * 4 + wid; n < N_NODES; n += gridDim.x * 4) {
        const float* xr = x + (size_t)n * F_IN;
        float acc = bs[lane];
        #pragma unroll
        for (int k = 0; k < F_IN; ++k)
            acc = fmaf(xr[k], Ws[k * H + lane], acc);
        h[(size_t)n * H + lane] = fmaxf(acc, 0.f);
    }
}

// ------------- edge stage: m = relu(h[src] + ea@We + be); agg[dst] += m -------------
__global__ __launch_bounds__(256) void k_edge(
        const int* __restrict__ ei, const float* __restrict__ ea,
        const float* __restrict__ We_l, const float* __restrict__ be_l,
        const float* __restrict__ h, float* __restrict__ agg)
{
    int lane  = threadIdx.x & 63;
    int gwave = (blockIdx.x * blockDim.x + threadIdx.x) >> 6;
    int nwave = (gridDim.x * blockDim.x) >> 6;
    // per-lane edge-weight column (wave-invariant, hoisted out of loop)
    float w0 = We_l[0 * H + lane];
    float w1 = We_l[1 * H + lane];
    float w2 = We_l[2 * H + lane];
    float w3 = We_l[3 * H + lane];
    float bf = be_l[lane];
    for (int e = gwave; e < N_EDGES; e += nwave) {
        int src = ei[e];
        int dst = ei[N_EDGES + e];
        float4 a = *reinterpret_cast<const float4*>(ea + (size_t)e * 4);
        float ev = fmaf(a.x, w0, fmaf(a.y, w1, fmaf(a.z, w2, fmaf(a.w, w3, bf))));
        float m  = fmaxf(h[(size_t)src * H + lane] + ev, 0.f);
        atomicAdd(agg + (size_t)dst * H + lane, m);
    }
}

// ------------- node MLP: h = relu(relu((h+agg)@W1+b1)@W2+b2), in place -------------
__global__ __launch_bounds__(256) void k_mlp(
        const float* __restrict__ W1l, const float* __restrict__ b1l,
        const float* __restrict__ W2l, const float* __restrict__ b2l,
        const float* __restrict__ agg, float* __restrict__ h)
{
    __shared__ float W1s[H * H];
    __shared__ float W2s[H * H];
    __shared__ float b1s[H], b2s[H];
    int tid = threadIdx.x;
    for (int i = tid; i < H * H; i += 256) { W1s[i] = W1l[i]; W2s[i] = W2l[i]; }
    if (tid < H) { b1s[tid] = b1l[tid]; b2s[tid] = b2l[tid]; }
    __syncthreads();
    int lane = tid & 63;
    int wid  = tid >> 6;
    for (int n = blockIdx.x * 4 + wid; n < N_NODES; n += gridDim.x * 4) {
        size_t base = (size_t)n * H + lane;
        float z = h[base] + agg[base];
        float acc = b1s[lane];
        #pragma unroll 16
        for (int j = 0; j < H; ++j)
            acc = fmaf(__shfl(z, j), W1s[j * H + lane], acc);
        float z1 = fmaxf(acc, 0.f);
        float acc2 = b2s[lane];
        #pragma unroll 16
        for (int j = 0; j < H; ++j)
            acc2 = fmaf(__shfl(z1, j), W2s[j * H + lane], acc2);
        h[base] = fmaxf(acc2, 0.f);
    }
}

// ------------------- mean pool accumulate (atomics into gsum/gcnt) -------------------
__global__ __launch_bounds__(256) void k_pool(
        const float* __restrict__ h, const int* __restrict__ batch,
        float* __restrict__ gsum, float* __restrict__ gcnt)
{
    int lane  = threadIdx.x & 63;
    int gwave = (blockIdx.x * blockDim.x + threadIdx.x) >> 6;
    int nwave = (gridDim.x * blockDim.x) >> 6;
    for (int n = gwave; n < N_NODES; n += nwave) {
        int b = batch[n];
        atomicAdd(gsum + (size_t)b * H + lane, h[(size_t)n * H + lane]);
        if (lane == 0) atomicAdd(gcnt + b, 1.0f);
    }
}

// ------------- finalize: mean, LayerNorm over H, out = g @ W_out + b_out -------------
__global__ __launch_bounds__(64) void k_final(
        const float* __restrict__ gsum, const float* __restrict__ gcnt,
        const float* __restrict__ Wout, const float* __restrict__ bout,
        float* __restrict__ out)
{
    int g    = blockIdx.x;
    int lane = threadIdx.x;
    float c = gcnt[g];
    float v = gsum[(size_t)g * H + lane] / fmaxf(c, 1.0f);
    float s = v;
    #pragma unroll
    for (int off = 32; off; off >>= 1) s += __shfl_xor(s, off);
    float mu = s * (1.0f / H);
    float d  = v - mu;
    float s2 = d * d;
    #pragma unroll
    for (int off = 32; off; off >>= 1) s2 += __shfl_xor(s2, off);
    float var = s2 * (1.0f / H);
    float y = d * rsqrtf(var + LN_EPS);
    float p = y * Wout[lane];
    #pragma unroll
    for (int off = 32; off; off >>= 1) p += __shfl_xor(p, off);
    if (lane == 0) out[g] = p + bout[0];
}

extern "C" void kernel_launch(void* const* d_in, const int* in_sizes, int n_in,
                              void* d_out, int out_size, void* d_ws, size_t ws_size,
                              hipStream_t stream)
{
    const float* x     = (const float*)d_in[0];
    const int*   ei    = (const int*)  d_in[1];
    const float* ea    = (const float*)d_in[2];
    const int*   batch = (const int*)  d_in[3];
    const float* Win   = (const float*)d_in[4];
    const float* bin   = (const float*)d_in[5];
    const float* We    = (const float*)d_in[6];
    const float* be    = (const float*)d_in[7];
    const float* W1    = (const float*)d_in[8];
    const float* b1    = (const float*)d_in[9];
    const float* W2    = (const float*)d_in[10];
    const float* b2    = (const float*)d_in[11];
    const float* Wout  = (const float*)d_in[12];
    const float* bout  = (const float*)d_in[13];
    float* out = (float*)d_out;

    char* ws = (char*)d_ws;
    const size_t HB = (size_t)N_NODES * H * sizeof(float);   // 25.6 MB
    float* h    = (float*)ws;
    float* agg  = (float*)(ws + HB);
    float* gsum = (float*)(ws + 2 * HB);
    float* gcnt = gsum + (size_t)N_GRAPHS * H;

    k_input_proj<<<1024, 256, 0, stream>>>(x, Win, bin, h);
    for (int l = 0; l < N_LAYERS; ++l) {
        hipMemsetAsync(agg, 0, HB, stream);
        k_edge<<<2048, 256, 0, stream>>>(ei, ea, We + (size_t)l * 4 * H,
                                         be + (size_t)l * H, h, agg);
        k_mlp<<<1024, 256, 0, stream>>>(W1 + (size_t)l * H * H, b1 + (size_t)l * H,
                                        W2 + (size_t)l * H * H, b2 + (size_t)l * H,
                                        agg, h);
    }
    hipMemsetAsync(gsum, 0, ((size_t)N_GRAPHS * H + N_GRAPHS) * sizeof(float), stream);
    k_pool<<<2048, 256, 0, stream>>>(h, batch, gsum, gcnt);
    k_final<<<N_GRAPHS, 64, 0, stream>>>(gsum, gcnt, Wout, bout, out);
}

// Round 3
// 1333.888 us; speedup vs baseline: 2.0949x; 2.0949x over previous
//
#include <hip/hip_runtime.h>

#define N_NODES  100000
#define N_EDGES  1600000
#define N_GRAPHS 2000
#define F_IN     32
#define H        64
#define N_LAYERS 5
#define LN_EPS   1e-5f

#define SCAN_BLK 512
#define SCAN_EPB 2048                                  // 4 elems/thread
#define SCAN_NB  ((N_NODES + SCAN_EPB - 1) / SCAN_EPB) // 49 blocks

// ---------------- CSR build: histogram of dst ----------------
__global__ __launch_bounds__(256) void k_hist(const int* __restrict__ ei,
                                              int* __restrict__ cnt)
{
    int i = blockIdx.x * 256 + threadIdx.x;
    int stride = gridDim.x * 256;
    for (int e = i; e < N_EDGES; e += stride)
        atomicAdd(&cnt[ei[N_EDGES + e]], 1);
}

// ---------------- CSR build: block-level exclusive scan ----------------
__global__ __launch_bounds__(SCAN_BLK) void k_scan1(const int* __restrict__ cnt,
                                                    int* __restrict__ rp,
                                                    int* __restrict__ bsum)
{
    __shared__ int s[SCAN_BLK];
    int tid = threadIdx.x;
    int base = blockIdx.x * SCAN_EPB + tid * 4;
    int v0 = (base + 0 < N_NODES) ? cnt[base + 0] : 0;
    int v1 = (base + 1 < N_NODES) ? cnt[base + 1] : 0;
    int v2 = (base + 2 < N_NODES) ? cnt[base + 2] : 0;
    int v3 = (base + 3 < N_NODES) ? cnt[base + 3] : 0;
    int tsum = v0 + v1 + v2 + v3;
    s[tid] = tsum;
    __syncthreads();
    for (int off = 1; off < SCAN_BLK; off <<= 1) {
        int t = (tid >= off) ? s[tid - off] : 0;
        __syncthreads();
        s[tid] += t;
        __syncthreads();
    }
    int excl = s[tid] - tsum;
    if (base + 0 < N_NODES) rp[base + 0] = excl;
    if (base + 1 < N_NODES) rp[base + 1] = excl + v0;
    if (base + 2 < N_NODES) rp[base + 2] = excl + v0 + v1;
    if (base + 3 < N_NODES) rp[base + 3] = excl + v0 + v1 + v2;
    if (tid == SCAN_BLK - 1) bsum[blockIdx.x] = s[tid];
}

__global__ void k_scan2(int* __restrict__ bsum)
{
    if (threadIdx.x == 0 && blockIdx.x == 0) {
        int acc = 0;
        for (int b = 0; b < SCAN_NB; ++b) { int t = bsum[b]; bsum[b] = acc; acc += t; }
    }
}

__global__ __launch_bounds__(SCAN_BLK) void k_scan3(int* __restrict__ rp,
                                                    const int* __restrict__ bsum,
                                                    int* __restrict__ cursor)
{
    int tid = threadIdx.x, blk = blockIdx.x;
    int add = bsum[blk];
    int base = blk * SCAN_EPB + tid * 4;
    #pragma unroll
    for (int i = 0; i < 4; ++i) {
        int idx = base + i;
        if (idx < N_NODES) { int v = rp[idx] + add; rp[idx] = v; cursor[idx] = v; }
    }
    if (blk == 0 && tid == 0) rp[N_NODES] = N_EDGES;
}

// ---------------- CSR build: scatter edges into dst-sorted order ----------------
__global__ __launch_bounds__(256) void k_scatter(const int* __restrict__ ei,
                                                 const float* __restrict__ ea,
                                                 int* __restrict__ cursor,
                                                 int* __restrict__ srcs,
                                                 float4* __restrict__ eas)
{
    int i = blockIdx.x * 256 + threadIdx.x;
    int stride = gridDim.x * 256;
    for (int e = i; e < N_EDGES; e += stride) {
        int s = ei[e];
        int d = ei[N_EDGES + e];
        int pos = atomicAdd(&cursor[d], 1);
        srcs[pos] = s;
        eas[pos] = reinterpret_cast<const float4*>(ea)[e];
    }
}

// ---------------- input projection: h = relu(x @ W_in + b_in) ----------------
__global__ __launch_bounds__(256) void k_input_proj(
        const float* __restrict__ x, const float* __restrict__ Win,
        const float* __restrict__ bin, float* __restrict__ h)
{
    __shared__ float Ws[F_IN * H];
    __shared__ float bs[H];
    int tid = threadIdx.x;
    for (int i = tid; i < F_IN * H; i += 256) Ws[i] = Win[i];
    if (tid < H) bs[tid] = bin[tid];
    __syncthreads();
    int lane = tid & 63;
    int wid  = tid >> 6;
    for (int n = blockIdx.x * 4 + wid; n < N_NODES; n += gridDim.x * 4) {
        const float* xr = x + (size_t)n * F_IN;
        float acc = bs[lane];
        #pragma unroll
        for (int k = 0; k < F_IN; ++k)
            acc = fmaf(xr[k], Ws[k * H + lane], acc);
        h[(size_t)n * H + lane] = fmaxf(acc, 0.f);
    }
}

// ------- aggregation (CSR, no atomics): z[n] = h[n] + sum_in relu(h[src]+e) -------
__global__ __launch_bounds__(256) void k_agg(
        const int* __restrict__ rp, const int* __restrict__ srcs,
        const float4* __restrict__ eas,
        const float* __restrict__ We_l, const float* __restrict__ be_l,
        const float* __restrict__ h, float* __restrict__ z)
{
    int lane  = threadIdx.x & 63;
    int gwave = (blockIdx.x * blockDim.x + threadIdx.x) >> 6;
    int nwave = (gridDim.x * blockDim.x) >> 6;
    float w0 = We_l[0 * H + lane];
    float w1 = We_l[1 * H + lane];
    float w2 = We_l[2 * H + lane];
    float w3 = We_l[3 * H + lane];
    float bf = be_l[lane];
    for (int n = gwave; n < N_NODES; n += nwave) {
        int j0 = rp[n], j1 = rp[n + 1];
        float acc = 0.f;
        for (int j = j0; j < j1; ++j) {
            int src  = srcs[j];
            float4 a = eas[j];
            float ev = fmaf(a.x, w0, fmaf(a.y, w1, fmaf(a.z, w2, fmaf(a.w, w3, bf))));
            acc += fmaxf(h[(size_t)src * H + lane] + ev, 0.f);
        }
        z[(size_t)n * H + lane] = h[(size_t)n * H + lane] + acc;
    }
}

// ------- tiled node MLP, in place: z = relu(relu(z@W1+b1)@W2+b2), 64 nodes/block -------
__global__ __launch_bounds__(256) void k_mlp2(
        const float* __restrict__ W1l, const float* __restrict__ b1l,
        const float* __restrict__ W2l, const float* __restrict__ b2l,
        float* __restrict__ z)
{
    __shared__ float zs[64][65];
    __shared__ float z2[64][65];
    int tid = threadIdx.x;
    int n0  = blockIdx.x * 64;
    int nrows = N_NODES - n0; if (nrows > 64) nrows = 64;

    for (int i = tid; i < 64 * 16; i += 256) {
        int r = i >> 4, c4 = (i & 15) * 4;
        if (r < nrows) {
            float4 v = *reinterpret_cast<const float4*>(&z[(size_t)(n0 + r) * H + c4]);
            zs[r][c4] = v.x; zs[r][c4 + 1] = v.y; zs[r][c4 + 2] = v.z; zs[r][c4 + 3] = v.w;
        }
    }
    __syncthreads();

    int tr = (tid >> 4) * 4, tc = (tid & 15) * 4;
    float acc[4][4];
    #pragma unroll
    for (int i = 0; i < 4; ++i)
        #pragma unroll
        for (int j = 0; j < 4; ++j) acc[i][j] = b1l[tc + j];
    #pragma unroll 8
    for (int k = 0; k < H; ++k) {
        float4 w = *reinterpret_cast<const float4*>(&W1l[k * H + tc]);
        #pragma unroll
        for (int i = 0; i < 4; ++i) {
            float zr = zs[tr + i][k];
            acc[i][0] = fmaf(zr, w.x, acc[i][0]);
            acc[i][1] = fmaf(zr, w.y, acc[i][1]);
            acc[i][2] = fmaf(zr, w.z, acc[i][2]);
            acc[i][3] = fmaf(zr, w.w, acc[i][3]);
        }
    }
    #pragma unroll
    for (int i = 0; i < 4; ++i)
        #pragma unroll
        for (int j = 0; j < 4; ++j) z2[tr + i][tc + j] = fmaxf(acc[i][j], 0.f);
    __syncthreads();

    float acc2[4][4];
    #pragma unroll
    for (int i = 0; i < 4; ++i)
        #pragma unroll
        for (int j = 0; j < 4; ++j) acc2[i][j] = b2l[tc + j];
    #pragma unroll 8
    for (int k = 0; k < H; ++k) {
        float4 w = *reinterpret_cast<const float4*>(&W2l[k * H + tc]);
        #pragma unroll
        for (int i = 0; i < 4; ++i) {
            float zr = z2[tr + i][k];
            acc2[i][0] = fmaf(zr, w.x, acc2[i][0]);
            acc2[i][1] = fmaf(zr, w.y, acc2[i][1]);
            acc2[i][2] = fmaf(zr, w.z, acc2[i][2]);
            acc2[i][3] = fmaf(zr, w.w, acc2[i][3]);
        }
    }
    #pragma unroll
    for (int i = 0; i < 4; ++i) {
        if (tr + i < nrows) {
            float4 o;
            o.x = fmaxf(acc2[i][0], 0.f);
            o.y = fmaxf(acc2[i][1], 0.f);
            o.z = fmaxf(acc2[i][2], 0.f);
            o.w = fmaxf(acc2[i][3], 0.f);
            *reinterpret_cast<float4*>(&z[(size_t)(n0 + tr + i) * H + tc]) = o;
        }
    }
}

// ------------------- mean pool accumulate -------------------
__global__ __launch_bounds__(256) void k_pool(
        const float* __restrict__ h, const int* __restrict__ batch,
        float* __restrict__ gsum, float* __restrict__ gcnt)
{
    int lane  = threadIdx.x & 63;
    int gwave = (blockIdx.x * blockDim.x + threadIdx.x) >> 6;
    int nwave = (gridDim.x * blockDim.x) >> 6;
    for (int n = gwave; n < N_NODES; n += nwave) {
        int b = batch[n];
        atomicAdd(gsum + (size_t)b * H + lane, h[(size_t)n * H + lane]);
        if (lane == 0) atomicAdd(gcnt + b, 1.0f);
    }
}

// ------------- finalize: mean, LayerNorm, out = g @ W_out + b_out -------------
__global__ __launch_bounds__(64) void k_final(
        const float* __restrict__ gsum, const float* __restrict__ gcnt,
        const float* __restrict__ Wout, const float* __restrict__ bout,
        float* __restrict__ out)
{
    int g    = blockIdx.x;
    int lane = threadIdx.x;
    float c = gcnt[g];
    float v = gsum[(size_t)g * H + lane] / fmaxf(c, 1.0f);
    float s = v;
    #pragma unroll
    for (int off = 32; off; off >>= 1) s += __shfl_xor(s, off);
    float mu = s * (1.0f / H);
    float d  = v - mu;
    float s2 = d * d;
    #pragma unroll
    for (int off = 32; off; off >>= 1) s2 += __shfl_xor(s2, off);
    float var = s2 * (1.0f / H);
    float y = d * rsqrtf(var + LN_EPS);
    float p = y * Wout[lane];
    #pragma unroll
    for (int off = 32; off; off >>= 1) p += __shfl_xor(p, off);
    if (lane == 0) out[g] = p + bout[0];
}

extern "C" void kernel_launch(void* const* d_in, const int* in_sizes, int n_in,
                              void* d_out, int out_size, void* d_ws, size_t ws_size,
                              hipStream_t stream)
{
    const float* x     = (const float*)d_in[0];
    const int*   ei    = (const int*)  d_in[1];
    const float* ea    = (const float*)d_in[2];
    const int*   batch = (const int*)  d_in[3];
    const float* Win   = (const float*)d_in[4];
    const float* bin   = (const float*)d_in[5];
    const float* We    = (const float*)d_in[6];
    const float* be    = (const float*)d_in[7];
    const float* W1    = (const float*)d_in[8];
    const float* b1    = (const float*)d_in[9];
    const float* W2    = (const float*)d_in[10];
    const float* b2    = (const float*)d_in[11];
    const float* Wout  = (const float*)d_in[12];
    const float* bout  = (const float*)d_in[13];
    float* out = (float*)d_out;

    char* ws = (char*)d_ws;
    size_t off = 0;
    auto alloc = [&](size_t bytes) -> char* {
        char* p = ws + off;
        off += (bytes + 255) & ~(size_t)255;
        return p;
    };
    const size_t HB = (size_t)N_NODES * H * sizeof(float);   // 25.6 MB
    float*  h0     = (float*) alloc(HB);
    float*  h1     = (float*) alloc(HB);
    float4* eas    = (float4*)alloc((size_t)N_EDGES * sizeof(float4)); // 25.6 MB
    int*    srcs   = (int*)   alloc((size_t)N_EDGES * sizeof(int));    // 6.4 MB
    int*    rp     = (int*)   alloc((size_t)(N_NODES + 1) * sizeof(int));
    int*    cursor = (int*)   alloc((size_t)N_NODES * sizeof(int));
    int*    bsum   = (int*)   alloc((size_t)SCAN_NB * sizeof(int));
    float*  gsum   = (float*) alloc(((size_t)N_GRAPHS * H + N_GRAPHS) * sizeof(float));
    float*  gcnt   = gsum + (size_t)N_GRAPHS * H;

    // ---- CSR build (dst-sorted edge permutation, ea pre-permuted) ----
    hipMemsetAsync(cursor, 0, (size_t)N_NODES * sizeof(int), stream);
    k_hist<<<2048, 256, 0, stream>>>(ei, cursor);
    k_scan1<<<SCAN_NB, SCAN_BLK, 0, stream>>>(cursor, rp, bsum);
    k_scan2<<<1, 64, 0, stream>>>(bsum);
    k_scan3<<<SCAN_NB, SCAN_BLK, 0, stream>>>(rp, bsum, cursor);
    k_scatter<<<2048, 256, 0, stream>>>(ei, ea, cursor, srcs, eas);

    // ---- network ----
    k_input_proj<<<1024, 256, 0, stream>>>(x, Win, bin, h0);
    float* cur = h0;
    float* nxt = h1;
    for (int l = 0; l < N_LAYERS; ++l) {
        k_agg<<<2048, 256, 0, stream>>>(rp, srcs, eas,
                                        We + (size_t)l * 4 * H, be + (size_t)l * H,
                                        cur, nxt);
        k_mlp2<<<(N_NODES + 63) / 64, 256, 0, stream>>>(
                W1 + (size_t)l * H * H, b1 + (size_t)l * H,
                W2 + (size_t)l * H * H, b2 + (size_t)l * H, nxt);
        float* t = cur; cur = nxt; nxt = t;
    }

    hipMemsetAsync(gsum, 0, ((size_t)N_GRAPHS * H + N_GRAPHS) * sizeof(float), stream);
    k_pool<<<2048, 256, 0, stream>>>(cur, batch, gsum, gcnt);
    k_final<<<N_GRAPHS, 64, 0, stream>>>(gsum, gcnt, Wout, bout, out);
}

// Round 4
// 1318.459 us; speedup vs baseline: 2.1194x; 1.0117x over previous
//
#include <hip/hip_runtime.h>

#define N_NODES  100000
#define N_EDGES  1600000
#define N_GRAPHS 2000
#define F_IN     32
#define H        64
#define N_LAYERS 5
#define LN_EPS   1e-5f

#define SCAN_BLK 512
#define SCAN_EPB 2048                                  // 4 elems/thread
#define SCAN_NB  ((N_NODES + SCAN_EPB - 1) / SCAN_EPB) // 49 blocks

typedef unsigned short u16;

__device__ __forceinline__ float bf2f(u16 v) {
    union { unsigned u; float f; } c; c.u = ((unsigned)v) << 16; return c.f;
}
__device__ __forceinline__ u16 f2bf(float f) {   // round-to-nearest-even
    union { float f; unsigned u; } c; c.f = f;
    return (u16)((c.u + 0x7fffu + ((c.u >> 16) & 1u)) >> 16);
}

// ---------------- CSR build: histogram of dst ----------------
__global__ __launch_bounds__(256) void k_hist(const int* __restrict__ ei,
                                              int* __restrict__ cnt)
{
    int i = blockIdx.x * 256 + threadIdx.x;
    int stride = gridDim.x * 256;
    for (int e = i; e < N_EDGES; e += stride)
        atomicAdd(&cnt[ei[N_EDGES + e]], 1);
}

// ---------------- CSR build: block-level exclusive scan ----------------
__global__ __launch_bounds__(SCAN_BLK) void k_scan1(const int* __restrict__ cnt,
                                                    int* __restrict__ rp,
                                                    int* __restrict__ bsum)
{
    __shared__ int s[SCAN_BLK];
    int tid = threadIdx.x;
    int base = blockIdx.x * SCAN_EPB + tid * 4;
    int v0 = (base + 0 < N_NODES) ? cnt[base + 0] : 0;
    int v1 = (base + 1 < N_NODES) ? cnt[base + 1] : 0;
    int v2 = (base + 2 < N_NODES) ? cnt[base + 2] : 0;
    int v3 = (base + 3 < N_NODES) ? cnt[base + 3] : 0;
    int tsum = v0 + v1 + v2 + v3;
    s[tid] = tsum;
    __syncthreads();
    for (int off = 1; off < SCAN_BLK; off <<= 1) {
        int t = (tid >= off) ? s[tid - off] : 0;
        __syncthreads();
        s[tid] += t;
        __syncthreads();
    }
    int excl = s[tid] - tsum;
    if (base + 0 < N_NODES) rp[base + 0] = excl;
    if (base + 1 < N_NODES) rp[base + 1] = excl + v0;
    if (base + 2 < N_NODES) rp[base + 2] = excl + v0 + v1;
    if (base + 3 < N_NODES) rp[base + 3] = excl + v0 + v1 + v2;
    if (tid == SCAN_BLK - 1) bsum[blockIdx.x] = s[tid];
}

__global__ void k_scan2(int* __restrict__ bsum)
{
    if (threadIdx.x == 0 && blockIdx.x == 0) {
        int acc = 0;
        for (int b = 0; b < SCAN_NB; ++b) { int t = bsum[b]; bsum[b] = acc; acc += t; }
    }
}

__global__ __launch_bounds__(SCAN_BLK) void k_scan3(int* __restrict__ rp,
                                                    const int* __restrict__ bsum,
                                                    int* __restrict__ cursor)
{
    int tid = threadIdx.x, blk = blockIdx.x;
    int add = bsum[blk];
    int base = blk * SCAN_EPB + tid * 4;
    #pragma unroll
    for (int i = 0; i < 4; ++i) {
        int idx = base + i;
        if (idx < N_NODES) { int v = rp[idx] + add; rp[idx] = v; cursor[idx] = v; }
    }
    if (blk == 0 && tid == 0) rp[N_NODES] = N_EDGES;
}

// -------- CSR build: scatter edges into dst-sorted order (ea -> bf16) --------
__global__ __launch_bounds__(256) void k_scatter(const int* __restrict__ ei,
                                                 const float* __restrict__ ea,
                                                 int* __restrict__ cursor,
                                                 int* __restrict__ srcs,
                                                 ushort4* __restrict__ eab)
{
    int i = blockIdx.x * 256 + threadIdx.x;
    int stride = gridDim.x * 256;
    for (int e = i; e < N_EDGES; e += stride) {
        int s = ei[e];
        int d = ei[N_EDGES + e];
        int pos = atomicAdd(&cursor[d], 1);
        float4 a = reinterpret_cast<const float4*>(ea)[e];
        ushort4 o;
        o.x = f2bf(a.x); o.y = f2bf(a.y); o.z = f2bf(a.z); o.w = f2bf(a.w);
        srcs[pos] = s;
        eab[pos]  = o;
    }
}

// -------- graph rowptr from sorted batch (boundary detect, no atomics) --------
__global__ __launch_bounds__(256) void k_gptr(const int* __restrict__ batch,
                                              int* __restrict__ gp)
{
    int n = blockIdx.x * 256 + threadIdx.x;
    if (n >= N_NODES) return;
    int b  = batch[n];
    int bp = (n == 0) ? -1 : batch[n - 1];
    for (int g = bp + 1; g <= b; ++g) gp[g] = n;
    if (n == N_NODES - 1)
        for (int g = b + 1; g <= N_GRAPHS; ++g) gp[g] = N_NODES;
}

// ---------------- input projection: h = relu(x @ W_in + b_in) -> bf16 ----------------
__global__ __launch_bounds__(256) void k_input_proj(
        const float* __restrict__ x, const float* __restrict__ Win,
        const float* __restrict__ bin, u16* __restrict__ h)
{
    __shared__ float Ws[F_IN * H];
    __shared__ float bs[H];
    int tid = threadIdx.x;
    for (int i = tid; i < F_IN * H; i += 256) Ws[i] = Win[i];
    if (tid < H) bs[tid] = bin[tid];
    __syncthreads();
    int lane = tid & 63;
    int wid  = tid >> 6;
    for (int n = blockIdx.x * 4 + wid; n < N_NODES; n += gridDim.x * 4) {
        const float* xr = x + (size_t)n * F_IN;
        float acc = bs[lane];
        #pragma unroll
        for (int k = 0; k < F_IN; ++k)
            acc = fmaf(xr[k], Ws[k * H + lane], acc);
        h[(size_t)n * H + lane] = f2bf(fmaxf(acc, 0.f));
    }
}

// ---- fused layer: z = h + sum_in relu(h[src]+e@We+be); h' = relu(mlp(z)) ----
// 64-node tile per 256-thread block. Phase 1: wave-per-node aggregation into LDS.
// Phase 2: tiled 64x64 MLP (zs reused for hidden layer), bf16 output.
__global__ __launch_bounds__(256, 8) void k_layer(
        const int* __restrict__ rp, const int* __restrict__ srcs,
        const ushort4* __restrict__ eab,
        const float* __restrict__ We_l, const float* __restrict__ be_l,
        const float* __restrict__ W1l, const float* __restrict__ b1l,
        const float* __restrict__ W2l, const float* __restrict__ b2l,
        const u16* __restrict__ hin, u16* __restrict__ hout)
{
    __shared__ float zs[64][65];
    int tid  = threadIdx.x;
    int lane = tid & 63, w = tid >> 6;
    int n0   = blockIdx.x * 64;

    // phase 1: aggregate 16 nodes per wave
    float w0 = We_l[0 * H + lane];
    float w1 = We_l[1 * H + lane];
    float w2 = We_l[2 * H + lane];
    float w3 = We_l[3 * H + lane];
    float bfv = be_l[lane];
    for (int i = 0; i < 16; ++i) {
        int row = w * 16 + i;
        int n   = n0 + row;
        float acc = 0.f;
        if (n < N_NODES) {
            acc = bf2f(hin[(size_t)n * H + lane]);   // self term (eps=0 -> 1*h)
            int j1 = rp[n + 1];
            for (int j = rp[n]; j < j1; ++j) {
                int s = srcs[j];
                ushort4 a = eab[j];
                float ev = fmaf(bf2f(a.x), w0, fmaf(bf2f(a.y), w1,
                           fmaf(bf2f(a.z), w2, fmaf(bf2f(a.w), w3, bfv))));
                acc += fmaxf(bf2f(hin[(size_t)s * H + lane]) + ev, 0.f);
            }
        }
        zs[row][lane] = acc;
    }
    __syncthreads();

    // phase 2: MLP on the 64x64 tile
    int tr = (tid >> 4) * 4, tc = (tid & 15) * 4;
    float a1[4][4];
    #pragma unroll
    for (int i = 0; i < 4; ++i)
        #pragma unroll
        for (int j = 0; j < 4; ++j) a1[i][j] = b1l[tc + j];
    #pragma unroll 8
    for (int k = 0; k < H; ++k) {
        float4 wv = *reinterpret_cast<const float4*>(&W1l[k * H + tc]);
        #pragma unroll
        for (int i = 0; i < 4; ++i) {
            float zr = zs[tr + i][k];
            a1[i][0] = fmaf(zr, wv.x, a1[i][0]);
            a1[i][1] = fmaf(zr, wv.y, a1[i][1]);
            a1[i][2] = fmaf(zr, wv.z, a1[i][2]);
            a1[i][3] = fmaf(zr, wv.w, a1[i][3]);
        }
    }
    __syncthreads();                       // everyone done reading zs
    #pragma unroll
    for (int i = 0; i < 4; ++i)
        #pragma unroll
        for (int j = 0; j < 4; ++j) zs[tr + i][tc + j] = fmaxf(a1[i][j], 0.f);
    __syncthreads();

    float a2[4][4];
    #pragma unroll
    for (int i = 0; i < 4; ++i)
        #pragma unroll
        for (int j = 0; j < 4; ++j) a2[i][j] = b2l[tc + j];
    #pragma unroll 8
    for (int k = 0; k < H; ++k) {
        float4 wv = *reinterpret_cast<const float4*>(&W2l[k * H + tc]);
        #pragma unroll
        for (int i = 0; i < 4; ++i) {
            float zr = zs[tr + i][k];
            a2[i][0] = fmaf(zr, wv.x, a2[i][0]);
            a2[i][1] = fmaf(zr, wv.y, a2[i][1]);
            a2[i][2] = fmaf(zr, wv.z, a2[i][2]);
            a2[i][3] = fmaf(zr, wv.w, a2[i][3]);
        }
    }
    #pragma unroll
    for (int i = 0; i < 4; ++i) {
        int n = n0 + tr + i;
        if (n < N_NODES) {
            ushort4 o;
            o.x = f2bf(fmaxf(a2[i][0], 0.f));
            o.y = f2bf(fmaxf(a2[i][1], 0.f));
            o.z = f2bf(fmaxf(a2[i][2], 0.f));
            o.w = f2bf(fmaxf(a2[i][3], 0.f));
            *reinterpret_cast<ushort4*>(&hout[(size_t)n * H + tc]) = o;
        }
    }
}

// ------- fused pool + LN + head: one wave per graph (batch sorted -> rowptr) -------
__global__ __launch_bounds__(64) void k_poolfinal(
        const u16* __restrict__ hb, const int* __restrict__ gp,
        const float* __restrict__ Wout, const float* __restrict__ bout,
        float* __restrict__ out)
{
    int g = blockIdx.x, lane = threadIdx.x;
    int a = gp[g], b = gp[g + 1];
    float s = 0.f;
    for (int n = a; n < b; ++n) s += bf2f(hb[(size_t)n * H + lane]);
    float v = s / fmaxf((float)(b - a), 1.f);
    float t = v;
    #pragma unroll
    for (int off = 32; off; off >>= 1) t += __shfl_xor(t, off);
    float mu = t * (1.0f / H);
    float d  = v - mu;
    float s2 = d * d;
    #pragma unroll
    for (int off = 32; off; off >>= 1) s2 += __shfl_xor(s2, off);
    float var = s2 * (1.0f / H);
    float y = d * rsqrtf(var + LN_EPS);
    float p = y * Wout[lane];
    #pragma unroll
    for (int off = 32; off; off >>= 1) p += __shfl_xor(p, off);
    if (lane == 0) out[g] = p + bout[0];
}

extern "C" void kernel_launch(void* const* d_in, const int* in_sizes, int n_in,
                              void* d_out, int out_size, void* d_ws, size_t ws_size,
                              hipStream_t stream)
{
    const float* x     = (const float*)d_in[0];
    const int*   ei    = (const int*)  d_in[1];
    const float* ea    = (const float*)d_in[2];
    const int*   batch = (const int*)  d_in[3];
    const float* Win   = (const float*)d_in[4];
    const float* bin   = (const float*)d_in[5];
    const float* We    = (const float*)d_in[6];
    const float* be    = (const float*)d_in[7];
    const float* W1    = (const float*)d_in[8];
    const float* b1    = (const float*)d_in[9];
    const float* W2    = (const float*)d_in[10];
    const float* b2    = (const float*)d_in[11];
    const float* Wout  = (const float*)d_in[12];
    const float* bout  = (const float*)d_in[13];
    float* out = (float*)d_out;

    char* ws = (char*)d_ws;
    size_t off = 0;
    auto alloc = [&](size_t bytes) -> char* {
        char* p = ws + off;
        off += (bytes + 255) & ~(size_t)255;
        return p;
    };
    const size_t HBH = (size_t)N_NODES * H * sizeof(u16);    // 12.8 MB
    u16*     h0     = (u16*)    alloc(HBH);
    u16*     h1     = (u16*)    alloc(HBH);
    ushort4* eab    = (ushort4*)alloc((size_t)N_EDGES * sizeof(ushort4)); // 12.8 MB
    int*     srcs   = (int*)    alloc((size_t)N_EDGES * sizeof(int));     // 6.4 MB
    int*     rp     = (int*)    alloc((size_t)(N_NODES + 1) * sizeof(int));
    int*     cursor = (int*)    alloc((size_t)N_NODES * sizeof(int));
    int*     bsum   = (int*)    alloc((size_t)SCAN_NB * sizeof(int));
    int*     gp     = (int*)    alloc((size_t)(N_GRAPHS + 1) * sizeof(int));

    // ---- CSR build (dst-sorted edge permutation; ea pre-permuted to bf16) ----
    hipMemsetAsync(cursor, 0, (size_t)N_NODES * sizeof(int), stream);
    k_hist<<<2048, 256, 0, stream>>>(ei, cursor);
    k_scan1<<<SCAN_NB, SCAN_BLK, 0, stream>>>(cursor, rp, bsum);
    k_scan2<<<1, 64, 0, stream>>>(bsum);
    k_scan3<<<SCAN_NB, SCAN_BLK, 0, stream>>>(rp, bsum, cursor);
    k_scatter<<<2048, 256, 0, stream>>>(ei, ea, cursor, srcs, eab);
    k_gptr<<<(N_NODES + 255) / 256, 256, 0, stream>>>(batch, gp);

    // ---- network ----
    k_input_proj<<<1024, 256, 0, stream>>>(x, Win, bin, h0);
    u16* cur = h0;
    u16* nxt = h1;
    const int NBLK = (N_NODES + 63) / 64;
    for (int l = 0; l < N_LAYERS; ++l) {
        k_layer<<<NBLK, 256, 0, stream>>>(rp, srcs, eab,
                We + (size_t)l * 4 * H, be + (size_t)l * H,
                W1 + (size_t)l * H * H, b1 + (size_t)l * H,
                W2 + (size_t)l * H * H, b2 + (size_t)l * H,
                cur, nxt);
        u16* t = cur; cur = nxt; nxt = t;
    }

    k_poolfinal<<<N_GRAPHS, 64, 0, stream>>>(cur, gp, Wout, bout, out);
}

// Round 5
// 810.619 us; speedup vs baseline: 3.4472x; 1.6265x over previous
//
#include <hip/hip_runtime.h>

#define N_NODES  100000
#define N_EDGES  1600000
#define N_GRAPHS 2000
#define F_IN     32
#define H        64
#define N_LAYERS 5
#define LN_EPS   1e-5f

#define SCAN_BLK 512
#define SCAN_EPB 2048                                  // 4 elems/thread
#define SCAN_NB  ((N_NODES + SCAN_EPB - 1) / SCAN_EPB) // 49 blocks

typedef unsigned short u16;

__device__ __forceinline__ float bf2f(u16 v) {
    union { unsigned u; float f; } c; c.u = ((unsigned)v) << 16; return c.f;
}
__device__ __forceinline__ u16 f2bf(float f) {   // round-to-nearest-even
    union { float f; unsigned u; } c; c.f = f;
    return (u16)((c.u + 0x7fffu + ((c.u >> 16) & 1u)) >> 16);
}

// ---------------- CSR build: histogram of dst ----------------
__global__ __launch_bounds__(256) void k_hist(const int* __restrict__ ei,
                                              int* __restrict__ cnt)
{
    int i = blockIdx.x * 256 + threadIdx.x;
    int stride = gridDim.x * 256;
    for (int e = i; e < N_EDGES; e += stride)
        atomicAdd(&cnt[ei[N_EDGES + e]], 1);
}

// ---------------- CSR build: block-level exclusive scan ----------------
__global__ __launch_bounds__(SCAN_BLK) void k_scan1(const int* __restrict__ cnt,
                                                    int* __restrict__ rp,
                                                    int* __restrict__ bsum)
{
    __shared__ int s[SCAN_BLK];
    int tid = threadIdx.x;
    int base = blockIdx.x * SCAN_EPB + tid * 4;
    int v0 = (base + 0 < N_NODES) ? cnt[base + 0] : 0;
    int v1 = (base + 1 < N_NODES) ? cnt[base + 1] : 0;
    int v2 = (base + 2 < N_NODES) ? cnt[base + 2] : 0;
    int v3 = (base + 3 < N_NODES) ? cnt[base + 3] : 0;
    int tsum = v0 + v1 + v2 + v3;
    s[tid] = tsum;
    __syncthreads();
    for (int off = 1; off < SCAN_BLK; off <<= 1) {
        int t = (tid >= off) ? s[tid - off] : 0;
        __syncthreads();
        s[tid] += t;
        __syncthreads();
    }
    int excl = s[tid] - tsum;
    if (base + 0 < N_NODES) rp[base + 0] = excl;
    if (base + 1 < N_NODES) rp[base + 1] = excl + v0;
    if (base + 2 < N_NODES) rp[base + 2] = excl + v0 + v1;
    if (base + 3 < N_NODES) rp[base + 3] = excl + v0 + v1 + v2;
    if (tid == SCAN_BLK - 1) bsum[blockIdx.x] = s[tid];
}

__global__ void k_scan2(int* __restrict__ bsum)
{
    if (threadIdx.x == 0 && blockIdx.x == 0) {
        int acc = 0;
        for (int b = 0; b < SCAN_NB; ++b) { int t = bsum[b]; bsum[b] = acc; acc += t; }
    }
}

__global__ __launch_bounds__(SCAN_BLK) void k_scan3(int* __restrict__ rp,
                                                    const int* __restrict__ bsum,
                                                    int* __restrict__ cursor)
{
    int tid = threadIdx.x, blk = blockIdx.x;
    int add = bsum[blk];
    int base = blk * SCAN_EPB + tid * 4;
    #pragma unroll
    for (int i = 0; i < 4; ++i) {
        int idx = base + i;
        if (idx < N_NODES) { int v = rp[idx] + add; rp[idx] = v; cursor[idx] = v; }
    }
    if (blk == 0 && tid == 0) rp[N_NODES] = N_EDGES;
}

// -- CSR build: scatter edges into dst-sorted 16B records {src, bf16x2, bf16x2, 0} --
__global__ __launch_bounds__(256) void k_scatter(const int* __restrict__ ei,
                                                 const float* __restrict__ ea,
                                                 int* __restrict__ cursor,
                                                 int4* __restrict__ erec)
{
    int i = blockIdx.x * 256 + threadIdx.x;
    int stride = gridDim.x * 256;
    for (int e = i; e < N_EDGES; e += stride) {
        int s = ei[e];
        int d = ei[N_EDGES + e];
        float4 a = reinterpret_cast<const float4*>(ea)[e];
        unsigned a01 = (unsigned)f2bf(a.x) | ((unsigned)f2bf(a.y) << 16);
        unsigned a23 = (unsigned)f2bf(a.z) | ((unsigned)f2bf(a.w) << 16);
        int pos = atomicAdd(&cursor[d], 1);
        erec[pos] = make_int4(s, (int)a01, (int)a23, 0);
    }
}

// -------- graph rowptr from sorted batch (boundary detect, no atomics) --------
__global__ __launch_bounds__(256) void k_gptr(const int* __restrict__ batch,
                                              int* __restrict__ gp)
{
    int n = blockIdx.x * 256 + threadIdx.x;
    if (n >= N_NODES) return;
    int b  = batch[n];
    int bp = (n == 0) ? -1 : batch[n - 1];
    for (int g = bp + 1; g <= b; ++g) gp[g] = n;
    if (n == N_NODES - 1)
        for (int g = b + 1; g <= N_GRAPHS; ++g) gp[g] = N_NODES;
}

// ---------------- input projection: h = relu(x @ W_in + b_in) -> bf16 ----------------
__global__ __launch_bounds__(256) void k_input_proj(
        const float* __restrict__ x, const float* __restrict__ Win,
        const float* __restrict__ bin, u16* __restrict__ h)
{
    __shared__ float Ws[F_IN * H];
    __shared__ float bs[H];
    int tid = threadIdx.x;
    for (int i = tid; i < F_IN * H; i += 256) Ws[i] = Win[i];
    if (tid < H) bs[tid] = bin[tid];
    __syncthreads();
    int lane = tid & 63;
    int wid  = tid >> 6;
    for (int n = blockIdx.x * 4 + wid; n < N_NODES; n += gridDim.x * 4) {
        const float* xr = x + (size_t)n * F_IN;
        float acc = bs[lane];
        #pragma unroll
        for (int k = 0; k < F_IN; ++k)
            acc = fmaf(xr[k], Ws[k * H + lane], acc);
        h[(size_t)n * H + lane] = f2bf(fmaxf(acc, 0.f));
    }
}

// ---- fused layer: z = h + sum_in relu(h[src]+e@We+be); h' = relu(mlp(z)) ----
// Phase 1: 16-lane groups, 4 concurrent edge chains/wave, 2-deep prefetch.
// Phase 2: tiled 64x64 MLP on LDS z tile.
__global__ __launch_bounds__(256, 8) void k_layer(
        const int* __restrict__ rp, const int4* __restrict__ erec,
        const float* __restrict__ We_l, const float* __restrict__ be_l,
        const float* __restrict__ W1l, const float* __restrict__ b1l,
        const float* __restrict__ W2l, const float* __restrict__ b2l,
        const u16* __restrict__ hin, u16* __restrict__ hout)
{
    __shared__ float zs[64][65];
    int tid  = threadIdx.x;
    int lane = tid & 63, w = tid >> 6;
    int q = lane >> 4, r = lane & 15;     // group q in [0,4), lane-in-group r
    int n0 = blockIdx.x * 64;
    const ushort4* hin4 = reinterpret_cast<const ushort4*>(hin);

    // per-lane: We columns 4r..4r+3 (4 attr rows) + bias
    float4 wr0 = *reinterpret_cast<const float4*>(We_l + 0 * H + r * 4);
    float4 wr1 = *reinterpret_cast<const float4*>(We_l + 1 * H + r * 4);
    float4 wr2 = *reinterpret_cast<const float4*>(We_l + 2 * H + r * 4);
    float4 wr3 = *reinterpret_cast<const float4*>(We_l + 3 * H + r * 4);
    float4 bv  = *reinterpret_cast<const float4*>(be_l + r * 4);

    for (int t = 0; t < 4; ++t) {
        int row = w * 16 + t * 4 + q;
        int n   = n0 + row;
        float4 acc = make_float4(0.f, 0.f, 0.f, 0.f);
        if (n < N_NODES) {
            ushort4 hs = hin4[(size_t)n * 16 + r];     // self term (eps=0)
            acc.x = bf2f(hs.x); acc.y = bf2f(hs.y);
            acc.z = bf2f(hs.z); acc.w = bf2f(hs.w);
            int j = rp[n], j1 = rp[n + 1];
            if (j < j1) {
                int4 r0 = erec[j];
                int4 r1 = (j + 1 < j1) ? erec[j + 1] : r0;
                ushort4 hp = hin4[(size_t)r0.x * 16 + r];
                for (; j < j1; ++j) {
                    int4 c = r0; ushort4 hc = hp;
                    r0 = r1;
                    if (j + 2 < j1) r1 = erec[j + 2];
                    if (j + 1 < j1) hp = hin4[(size_t)r0.x * 16 + r];
                    float ax = bf2f((u16)(c.y & 0xffff));
                    float ay = bf2f((u16)(((unsigned)c.y) >> 16));
                    float az = bf2f((u16)(c.z & 0xffff));
                    float aw = bf2f((u16)(((unsigned)c.z) >> 16));
                    float4 ev;
                    ev.x = fmaf(ax, wr0.x, fmaf(ay, wr1.x, fmaf(az, wr2.x, fmaf(aw, wr3.x, bv.x))));
                    ev.y = fmaf(ax, wr0.y, fmaf(ay, wr1.y, fmaf(az, wr2.y, fmaf(aw, wr3.y, bv.y))));
                    ev.z = fmaf(ax, wr0.z, fmaf(ay, wr1.z, fmaf(az, wr2.z, fmaf(aw, wr3.z, bv.z))));
                    ev.w = fmaf(ax, wr0.w, fmaf(ay, wr1.w, fmaf(az, wr2.w, fmaf(aw, wr3.w, bv.w))));
                    acc.x += fmaxf(bf2f(hc.x) + ev.x, 0.f);
                    acc.y += fmaxf(bf2f(hc.y) + ev.y, 0.f);
                    acc.z += fmaxf(bf2f(hc.z) + ev.z, 0.f);
                    acc.w += fmaxf(bf2f(hc.w) + ev.w, 0.f);
                }
            }
        }
        zs[row][r * 4 + 0] = acc.x;
        zs[row][r * 4 + 1] = acc.y;
        zs[row][r * 4 + 2] = acc.z;
        zs[row][r * 4 + 3] = acc.w;
    }
    __syncthreads();

    // phase 2: MLP on the 64x64 tile
    int tr = (tid >> 4) * 4, tc = (tid & 15) * 4;
    float a1[4][4];
    #pragma unroll
    for (int i = 0; i < 4; ++i)
        #pragma unroll
        for (int j = 0; j < 4; ++j) a1[i][j] = b1l[tc + j];
    #pragma unroll 8
    for (int k = 0; k < H; ++k) {
        float4 wv = *reinterpret_cast<const float4*>(&W1l[k * H + tc]);
        #pragma unroll
        for (int i = 0; i < 4; ++i) {
            float zr = zs[tr + i][k];
            a1[i][0] = fmaf(zr, wv.x, a1[i][0]);
            a1[i][1] = fmaf(zr, wv.y, a1[i][1]);
            a1[i][2] = fmaf(zr, wv.z, a1[i][2]);
            a1[i][3] = fmaf(zr, wv.w, a1[i][3]);
        }
    }
    __syncthreads();
    #pragma unroll
    for (int i = 0; i < 4; ++i)
        #pragma unroll
        for (int j = 0; j < 4; ++j) zs[tr + i][tc + j] = fmaxf(a1[i][j], 0.f);
    __syncthreads();

    float a2[4][4];
    #pragma unroll
    for (int i = 0; i < 4; ++i)
        #pragma unroll
        for (int j = 0; j < 4; ++j) a2[i][j] = b2l[tc + j];
    #pragma unroll 8
    for (int k = 0; k < H; ++k) {
        float4 wv = *reinterpret_cast<const float4*>(&W2l[k * H + tc]);
        #pragma unroll
        for (int i = 0; i < 4; ++i) {
            float zr = zs[tr + i][k];
            a2[i][0] = fmaf(zr, wv.x, a2[i][0]);
            a2[i][1] = fmaf(zr, wv.y, a2[i][1]);
            a2[i][2] = fmaf(zr, wv.z, a2[i][2]);
            a2[i][3] = fmaf(zr, wv.w, a2[i][3]);
        }
    }
    #pragma unroll
    for (int i = 0; i < 4; ++i) {
        int n = n0 + tr + i;
        if (n < N_NODES) {
            ushort4 o;
            o.x = f2bf(fmaxf(a2[i][0], 0.f));
            o.y = f2bf(fmaxf(a2[i][1], 0.f));
            o.z = f2bf(fmaxf(a2[i][2], 0.f));
            o.w = f2bf(fmaxf(a2[i][3], 0.f));
            *reinterpret_cast<ushort4*>(&hout[(size_t)n * H + tc]) = o;
        }
    }
}

// ------- fused pool + LN + head: one wave per graph (batch sorted -> rowptr) -------
__global__ __launch_bounds__(64) void k_poolfinal(
        const u16* __restrict__ hb, const int* __restrict__ gp,
        const float* __restrict__ Wout, const float* __restrict__ bout,
        float* __restrict__ out)
{
    int g = blockIdx.x, lane = threadIdx.x;
    int a = gp[g], b = gp[g + 1];
    float s = 0.f;
    for (int n = a; n < b; ++n) s += bf2f(hb[(size_t)n * H + lane]);
    float v = s / fmaxf((float)(b - a), 1.f);
    float t = v;
    #pragma unroll
    for (int off = 32; off; off >>= 1) t += __shfl_xor(t, off);
    float mu = t * (1.0f / H);
    float d  = v - mu;
    float s2 = d * d;
    #pragma unroll
    for (int off = 32; off; off >>= 1) s2 += __shfl_xor(s2, off);
    float var = s2 * (1.0f / H);
    float y = d * rsqrtf(var + LN_EPS);
    float p = y * Wout[lane];
    #pragma unroll
    for (int off = 32; off; off >>= 1) p += __shfl_xor(p, off);
    if (lane == 0) out[g] = p + bout[0];
}

extern "C" void kernel_launch(void* const* d_in, const int* in_sizes, int n_in,
                              void* d_out, int out_size, void* d_ws, size_t ws_size,
                              hipStream_t stream)
{
    const float* x     = (const float*)d_in[0];
    const int*   ei    = (const int*)  d_in[1];
    const float* ea    = (const float*)d_in[2];
    const int*   batch = (const int*)  d_in[3];
    const float* Win   = (const float*)d_in[4];
    const float* bin   = (const float*)d_in[5];
    const float* We    = (const float*)d_in[6];
    const float* be    = (const float*)d_in[7];
    const float* W1    = (const float*)d_in[8];
    const float* b1    = (const float*)d_in[9];
    const float* W2    = (const float*)d_in[10];
    const float* b2    = (const float*)d_in[11];
    const float* Wout  = (const float*)d_in[12];
    const float* bout  = (const float*)d_in[13];
    float* out = (float*)d_out;

    char* ws = (char*)d_ws;
    size_t off = 0;
    auto alloc = [&](size_t bytes) -> char* {
        char* p = ws + off;
        off += (bytes + 255) & ~(size_t)255;
        return p;
    };
    const size_t HBH = (size_t)N_NODES * H * sizeof(u16);    // 12.8 MB
    u16*  h0     = (u16*) alloc(HBH);
    u16*  h1     = (u16*) alloc(HBH);
    int4* erec   = (int4*)alloc((size_t)N_EDGES * sizeof(int4)); // 25.6 MB
    int*  rp     = (int*) alloc((size_t)(N_NODES + 1) * sizeof(int));
    int*  cursor = (int*) alloc((size_t)N_NODES * sizeof(int));
    int*  bsum   = (int*) alloc((size_t)SCAN_NB * sizeof(int));
    int*  gp     = (int*) alloc((size_t)(N_GRAPHS + 1) * sizeof(int));

    // ---- CSR build (dst-sorted edge records, attrs pre-converted to bf16) ----
    hipMemsetAsync(cursor, 0, (size_t)N_NODES * sizeof(int), stream);
    k_hist<<<2048, 256, 0, stream>>>(ei, cursor);
    k_scan1<<<SCAN_NB, SCAN_BLK, 0, stream>>>(cursor, rp, bsum);
    k_scan2<<<1, 64, 0, stream>>>(bsum);
    k_scan3<<<SCAN_NB, SCAN_BLK, 0, stream>>>(rp, bsum, cursor);
    k_scatter<<<2048, 256, 0, stream>>>(ei, ea, cursor, erec);
    k_gptr<<<(N_NODES + 255) / 256, 256, 0, stream>>>(batch, gp);

    // ---- network ----
    k_input_proj<<<1024, 256, 0, stream>>>(x, Win, bin, h0);
    u16* cur = h0;
    u16* nxt = h1;
    const int NBLK = (N_NODES + 63) / 64;
    for (int l = 0; l < N_LAYERS; ++l) {
        k_layer<<<NBLK, 256, 0, stream>>>(rp, erec,
                We + (size_t)l * 4 * H, be + (size_t)l * H,
                W1 + (size_t)l * H * H, b1 + (size_t)l * H,
                W2 + (size_t)l * H * H, b2 + (size_t)l * H,
                cur, nxt);
        u16* t = cur; cur = nxt; nxt = t;
    }

    k_poolfinal<<<N_GRAPHS, 64, 0, stream>>>(cur, gp, Wout, bout, out);
}